// Round 14
// baseline (2578.634 us; speedup 1.0000x reference)
//
#include <hip/hip_runtime.h>
#include <hip/hip_bf16.h>

// R14 = r13 pipeline (unchanged, passing) + 4 ablation probes of the r13
// main loop (x16 reps each): full / noexp / nomfma / nostage.
// Probes write only to ws sink; real output path untouched.

constexpr int   NODES = 128;
constexpr int   DD    = 64;
constexpr int   CC    = 64;
constexpr int   KK    = 32;
constexpr float GAMMA = 1.0f / 64.0f;
constexpr float LOG2E = 1.4426950408889634f;
constexpr float C1    = 2.0f * GAMMA * LOG2E;
constexpr float GL    = GAMMA * LOG2E;

typedef __attribute__((ext_vector_type(8)))  short short8;
typedef __attribute__((ext_vector_type(16))) float f32x16;

#define MFMA(a, b, c) __builtin_amdgcn_mfma_f32_32x32x16_bf16((a), (b), (c), 0, 0, 0)

__device__ __forceinline__ float fexp2(float x) {
#if __has_builtin(__builtin_amdgcn_exp2f)
    return __builtin_amdgcn_exp2f(x);
#else
    return exp2f(x);
#endif
}

__device__ __forceinline__ unsigned short f2bf(float f) {
    union { float f; unsigned int u; } a; a.f = f;
    unsigned int u = a.u;
    return (unsigned short)((u + 0x7FFFu + ((u >> 16) & 1u)) >> 16);  // RNE
}

__device__ __forceinline__ void gl16(const void* g, void* l) {
    __builtin_amdgcn_global_load_lds(
        (const __attribute__((address_space(1))) char*)g,
        (__attribute__((address_space(3))) char*)l, 16, 0, 0);
}

// ---------------------------------------------------------------------------
// prep_atoms (r13 verbatim)
// ---------------------------------------------------------------------------
__global__ __launch_bounds__(256) void prep_atoms(const float* __restrict__ atoms,
                                                  short8* __restrict__ bfrag,
                                                  float* __restrict__ can,
                                                  float* __restrict__ kyy) {
    const int c = blockIdx.x, t = threadIdx.x;
    __shared__ float a[KK][DD + 1];
    __shared__ float an[KK];
    __shared__ float wred[4];

    const float* ac = atoms + (size_t)c * KK * DD;
    for (int i = t; i < KK * DD; i += 256) a[i >> 6][i & 63] = ac[i];
    __syncthreads();

    if (t < KK) {
        float s = 0.f;
#pragma unroll
        for (int d = 0; d < DD; ++d) s = fmaf(a[t][d], a[t][d], s);
        an[t] = s;
        can[c * KK + t] = -GL * s;
    }
    __syncthreads();

    {
        const int wv = t >> 6, l = t & 63;
        const int kp = l & 31, khh = l >> 5;
        short8 h;
#pragma unroll
        for (int j = 0; j < 8; ++j)
            h[j] = (short)f2bf(C1 * a[kp][wv * 16 + khh * 8 + j]);
        bfrag[(size_t)c * 256 + wv * 64 + l] = h;
    }

    {
        const int i = t >> 3, j0 = (t & 7) * 4;
        float s0 = 0, s1 = 0, s2 = 0, s3 = 0;
        for (int d = 0; d < DD; ++d) {
            const float aid = a[i][d];
            s0 = fmaf(aid, a[j0 + 0][d], s0);
            s1 = fmaf(aid, a[j0 + 1][d], s1);
            s2 = fmaf(aid, a[j0 + 2][d], s2);
            s3 = fmaf(aid, a[j0 + 3][d], s3);
        }
        const float ani = an[i];
        float s = fexp2(-GL * (ani + an[j0 + 0] - 2.f * s0))
                + fexp2(-GL * (ani + an[j0 + 1] - 2.f * s1))
                + fexp2(-GL * (ani + an[j0 + 2] - 2.f * s2))
                + fexp2(-GL * (ani + an[j0 + 3] - 2.f * s3));
#pragma unroll
        for (int off = 32; off; off >>= 1) s += __shfl_xor(s, off);
        if ((t & 63) == 0) wred[t >> 6] = s;
    }
    __syncthreads();
    if (t == 0) kyy[c] = (wred[0] + wred[1] + wred[2] + wred[3]) * (1.0f / (KK * KK));
}

// ---------------------------------------------------------------------------
// mmd_fused (r13 verbatim, passing)
// ---------------------------------------------------------------------------
__global__ __launch_bounds__(256, 4) void mmd_fused(const float* __restrict__ x,
                                                    const short8* __restrict__ bfrag,
                                                    const float* __restrict__ can,
                                                    const float* __restrict__ kyy,
                                                    float* __restrict__ out) {
    const int bid = blockIdx.x, b = bid >> 2, cq = bid & 3;
    const int t = threadIdx.x, w = t >> 6, l = t & 63;
    const int l31 = l & 31, kh = l >> 5;

    __shared__ short8 Bb[2][4][256];
    __shared__ float  part16[4][20][16];
    __shared__ float  nl[NODES];
    __shared__ float  sxy_s[16];
    __shared__ float  kxx_s;

    float v[32];
    {
        const float* xr = x + ((size_t)(b * NODES + w * 32 + l31)) * DD + kh * 8;
#pragma unroll
        for (int kt = 0; kt < 4; ++kt) {
            const float4 p0 = *reinterpret_cast<const float4*>(xr + kt * 16);
            const float4 p1 = *reinterpret_cast<const float4*>(xr + kt * 16 + 4);
            v[kt*8+0]=p0.x; v[kt*8+1]=p0.y; v[kt*8+2]=p0.z; v[kt*8+3]=p0.w;
            v[kt*8+4]=p1.x; v[kt*8+5]=p1.y; v[kt*8+6]=p1.z; v[kt*8+7]=p1.w;
        }
    }
    float xn = 0.f;
#pragma unroll
    for (int i = 0; i < 32; ++i) xn = fmaf(v[i], v[i], xn);
    xn += __shfl_xor(xn, 32);
    if (l < 32) nl[w * 32 + l] = -GL * xn;

    short8 A[4];
#pragma unroll
    for (int kt = 0; kt < 4; ++kt) {
        short8 h;
#pragma unroll
        for (int j = 0; j < 8; ++j) h[j] = (short)f2bf(v[kt * 8 + j]);
        A[kt] = h;
        Bb[0][w][kt * 64 + l] = h;
    }

    float cav[16];
#pragma unroll
    for (int j = 0; j < 16; ++j) cav[j] = can[(cq * 16 + j) * KK + l31];

    __syncthreads();

    f32x16 cx;
    {
        const float* nb = &nl[w * 32 + 4 * kh];
#pragma unroll
        for (int q = 0; q < 4; ++q) {
            const float4 vq = *reinterpret_cast<const float4*>(nb + 8 * q);
            cx[4*q+0] = vq.x; cx[4*q+1] = vq.y; cx[4*q+2] = vq.z; cx[4*q+3] = vq.w;
        }
    }

    const short8* bq = bfrag + (size_t)(cq * 16) * 256;

#pragma unroll
    for (int s = 0; s < 5; ++s) {
        if (s < 4) {
            const short8* src = bq + (size_t)(s * 4 + w) * 256;
#pragma unroll
            for (int q = 0; q < 4; ++q)
                gl16(src + q * 64 + l, &Bb[(s + 1) & 1][w][q * 64]);
        }
#pragma unroll
        for (int p = 0; p < 4; ++p) {
            short8 Bt[4];
#pragma unroll
            for (int kt = 0; kt < 4; ++kt) Bt[kt] = Bb[s & 1][p][kt * 64 + l];

            float ssum;
            if (s == 0) {
                f32x16 acc = {};
#pragma unroll
                for (int kt = 0; kt < 4; ++kt) acc = MFMA(A[kt], Bt[kt], acc);
                const float ec0 = fexp2(nl[p * 32 + l31]);
                float sa = 0.f, sb = 0.f;
#pragma unroll
                for (int r = 0; r < 16; r += 2) {
                    sa += fexp2(fmaf(C1, acc[r],     cx[r]));
                    sb += fexp2(fmaf(C1, acc[r + 1], cx[r + 1]));
                }
                ssum = (sa + sb) * ec0;
            } else {
                const int j = (s - 1) * 4 + p;
                f32x16 acc;
#pragma unroll
                for (int r = 0; r < 16; ++r) acc[r] = cx[r] + cav[j];
#pragma unroll
                for (int kt = 0; kt < 4; ++kt) acc = MFMA(A[kt], Bt[kt], acc);
                float sa = 0.f, sb = 0.f;
#pragma unroll
                for (int r = 0; r < 16; r += 2) {
                    sa += fexp2(acc[r]);
                    sb += fexp2(acc[r + 1]);
                }
                ssum = sa + sb;
            }
            ssum += __shfl_xor(ssum, 32);
            ssum += __shfl_xor(ssum, 16);
            if (l < 16) part16[w][s * 4 + p][l] = ssum;
        }
        __syncthreads();
    }

    {
        const int o = t >> 4, g = t & 15;
        float s1 = part16[0][4 + o][g] + part16[1][4 + o][g]
                 + part16[2][4 + o][g] + part16[3][4 + o][g];
        s1 += __shfl_xor(s1, 8);
        s1 += __shfl_xor(s1, 4);
        s1 += __shfl_xor(s1, 2);
        s1 += __shfl_xor(s1, 1);
        if (g == 0) sxy_s[o] = s1;
    }
    if (t < 16) {
        float kx = 0.f;
#pragma unroll
        for (int ww = 0; ww < 4; ++ww)
#pragma unroll
            for (int q = 0; q < 4; ++q) kx += part16[ww][q][t];
        kx += __shfl_xor(kx, 8);
        kx += __shfl_xor(kx, 4);
        kx += __shfl_xor(kx, 2);
        kx += __shfl_xor(kx, 1);
        if (t == 0) kxx_s = kx;
    }
    __syncthreads();
    if (t < 16) {
        out[(size_t)b * CC + cq * 16 + t] =
            kxx_s * (1.0f / 16384.0f) + kyy[cq * 16 + t] - sxy_s[t] * (1.0f / 2048.0f);
    }
}

// ---------------------------------------------------------------------------
// Probe body: r13 loop x REP. V=0 full, V=1 noexp, V=2 nomfma (Bt kept live
// via int sink), V=3 nostage (no gl16). Writes to ws sink only.
// ---------------------------------------------------------------------------
template<int V, int REP>
__device__ __forceinline__ void probe_body(const float* __restrict__ x,
                                           const short8* __restrict__ bfrag,
                                           const float* __restrict__ can,
                                           float* __restrict__ sink) {
    const int bid = blockIdx.x, b = bid >> 2, cq = bid & 3;
    const int t = threadIdx.x, w = t >> 6, l = t & 63;
    const int l31 = l & 31, kh = l >> 5;

    __shared__ short8 Bb[2][4][256];
    __shared__ float  part16[4][20][16];
    __shared__ float  nl[NODES];

    // prologue (outside reps) — same shape as r13
    float v[32];
    {
        const float* xr = x + ((size_t)(b * NODES + w * 32 + l31)) * DD + kh * 8;
#pragma unroll
        for (int kt = 0; kt < 4; ++kt) {
            const float4 p0 = *reinterpret_cast<const float4*>(xr + kt * 16);
            const float4 p1 = *reinterpret_cast<const float4*>(xr + kt * 16 + 4);
            v[kt*8+0]=p0.x; v[kt*8+1]=p0.y; v[kt*8+2]=p0.z; v[kt*8+3]=p0.w;
            v[kt*8+4]=p1.x; v[kt*8+5]=p1.y; v[kt*8+6]=p1.z; v[kt*8+7]=p1.w;
        }
    }
    float xn = 0.f;
#pragma unroll
    for (int i = 0; i < 32; ++i) xn = fmaf(v[i], v[i], xn);
    xn += __shfl_xor(xn, 32);
    if (l < 32) nl[w * 32 + l] = -GL * xn;

    short8 A[4];
#pragma unroll
    for (int kt = 0; kt < 4; ++kt) {
        short8 h;
#pragma unroll
        for (int j = 0; j < 8; ++j) h[j] = (short)f2bf(v[kt * 8 + j]);
        A[kt] = h;
        Bb[0][w][kt * 64 + l] = h;
    }
    float cav[16];
#pragma unroll
    for (int j = 0; j < 16; ++j) cav[j] = can[(cq * 16 + j) * KK + l31];
    __syncthreads();

    f32x16 cx;
    {
        const float* nb = &nl[w * 32 + 4 * kh];
#pragma unroll
        for (int q = 0; q < 4; ++q) {
            const float4 vq = *reinterpret_cast<const float4*>(nb + 8 * q);
            cx[4*q+0] = vq.x; cx[4*q+1] = vq.y; cx[4*q+2] = vq.z; cx[4*q+3] = vq.w;
        }
    }

    const short8* bq = bfrag + (size_t)(cq * 16) * 256;
    int idum = 0;

    for (int rep = 0; rep < REP; ++rep) {
#pragma unroll
        for (int s = 0; s < 5; ++s) {
            if (V != 3 && s < 4) {
                const short8* src = bq + (size_t)(s * 4 + w) * 256;
#pragma unroll
                for (int q = 0; q < 4; ++q)
                    gl16(src + q * 64 + l, &Bb[(s + 1) & 1][w][q * 64]);
            }
#pragma unroll
            for (int p = 0; p < 4; ++p) {
                short8 Bt[4];
#pragma unroll
                for (int kt = 0; kt < 4; ++kt) Bt[kt] = Bb[s & 1][p][kt * 64 + l];

                float ssum;
                if (V == 2) {
                    // no MFMA: keep ds_reads live via int sink; exps on acc-init
                    idum += (int)Bt[0][0] + (int)Bt[1][0] + (int)Bt[2][0] + (int)Bt[3][0];
                    const int j = (s * 4 + p) & 15;
                    f32x16 acc;
#pragma unroll
                    for (int r = 0; r < 16; ++r) acc[r] = cx[r] + cav[j];
                    float sa = 0.f, sb = 0.f;
#pragma unroll
                    for (int r = 0; r < 16; r += 2) {
                        sa += fexp2(acc[r]);
                        sb += fexp2(acc[r + 1]);
                    }
                    ssum = sa + sb;
                } else if (s == 0) {
                    f32x16 acc = {};
#pragma unroll
                    for (int kt = 0; kt < 4; ++kt) acc = MFMA(A[kt], Bt[kt], acc);
                    if (V == 1) {
                        ssum = acc[0] + acc[5] + acc[10] + acc[15];   // no exp
                    } else {
                        const float ec0 = fexp2(nl[p * 32 + l31]);
                        float sa = 0.f, sb = 0.f;
#pragma unroll
                        for (int r = 0; r < 16; r += 2) {
                            sa += fexp2(fmaf(C1, acc[r],     cx[r]));
                            sb += fexp2(fmaf(C1, acc[r + 1], cx[r + 1]));
                        }
                        ssum = (sa + sb) * ec0;
                    }
                } else {
                    const int j = (s - 1) * 4 + p;
                    f32x16 acc;
#pragma unroll
                    for (int r = 0; r < 16; ++r) acc[r] = cx[r] + cav[j];
#pragma unroll
                    for (int kt = 0; kt < 4; ++kt) acc = MFMA(A[kt], Bt[kt], acc);
                    if (V == 1) {
                        ssum = acc[0] + acc[5] + acc[10] + acc[15];   // no exp
                    } else {
                        float sa = 0.f, sb = 0.f;
#pragma unroll
                        for (int r = 0; r < 16; r += 2) {
                            sa += fexp2(acc[r]);
                            sb += fexp2(acc[r + 1]);
                        }
                        ssum = sa + sb;
                    }
                }
                ssum += __shfl_xor(ssum, 32);
                ssum += __shfl_xor(ssum, 16);
                if (l < 16) part16[w][s * 4 + p][l] = ssum;
            }
            __syncthreads();
        }
    }

    asm volatile("" :: "v"(idum));
    if (t < 64) {
        float acm = 0.f;
#pragma unroll
        for (int ww = 0; ww < 4; ++ww)
            for (int i = 0; i < 20; ++i) acm += part16[ww][i][t & 15];
        sink[bid * 64 + t] = acm + (float)idum;
    }
}

__global__ __launch_bounds__(256, 4) void probe_full(const float* x, const short8* bf,
                                                     const float* can, float* sink) {
    probe_body<0, 16>(x, bf, can, sink);
}
__global__ __launch_bounds__(256, 4) void probe_noexp(const float* x, const short8* bf,
                                                      const float* can, float* sink) {
    probe_body<1, 16>(x, bf, can, sink);
}
__global__ __launch_bounds__(256, 4) void probe_nomfma(const float* x, const short8* bf,
                                                       const float* can, float* sink) {
    probe_body<2, 16>(x, bf, can, sink);
}
__global__ __launch_bounds__(256, 4) void probe_nostage(const float* x, const short8* bf,
                                                        const float* can, float* sink) {
    probe_body<3, 16>(x, bf, can, sink);
}

extern "C" void kernel_launch(void* const* d_in, const int* in_sizes, int n_in,
                              void* d_out, int out_size, void* d_ws, size_t ws_size,
                              hipStream_t stream) {
    const float* x     = (const float*)d_in[0];   // [32768, 64]
    const float* atoms = (const float*)d_in[1];   // [64, 32, 64]
    float* out = (float*)d_out;                   // [256, 64]

    char* ws = (char*)d_ws;
    short8* bfrag = (short8*)(ws);                        // 256 KiB
    float*  can   = (float*) (ws + 262144);               // 8 KiB
    float*  kyy   = (float*) (ws + 270336);               // 256 B
    float*  sink  = (float*) (ws + (1u << 20));           // 256 KiB probe sink

    prep_atoms<<<dim3(CC),   dim3(256), 0, stream>>>(atoms, bfrag, can, kyy);
    mmd_fused <<<dim3(1024), dim3(256), 0, stream>>>(x, bfrag, can, kyy, out);

    probe_full   <<<dim3(1024), dim3(256), 0, stream>>>(x, bfrag, can, sink);
    probe_noexp  <<<dim3(1024), dim3(256), 0, stream>>>(x, bfrag, can, sink);
    probe_nomfma <<<dim3(1024), dim3(256), 0, stream>>>(x, bfrag, can, sink);
    probe_nostage<<<dim3(1024), dim3(256), 0, stream>>>(x, bfrag, can, sink);
}

// Round 15
// 29.291 us; speedup vs baseline: 88.0342x; 88.0342x over previous
//
#include <hip/hip_runtime.h>
#include <hip/hip_bf16.h>

// out[b][c] = kxx_mean[b] + kyy[c] - 2*kxy_mean[b][c]
// x[32768][64] f32, atoms[64][32][64] f32, out[256][64] f32.
// R15: barrier-free main loop. B-frags read global->reg (2-deep prefetch),
// no LDS staging, 2 barriers total. kxx via one LDS A-exchange. Single-pass
// bf16 MFMA, C1-scaled B, acc-init = cx+ca, bare-exp epilogue (all validated).

constexpr int   NODES = 128;
constexpr int   DD    = 64;
constexpr int   CC    = 64;
constexpr int   KK    = 32;
constexpr float GAMMA = 1.0f / 64.0f;
constexpr float LOG2E = 1.4426950408889634f;
constexpr float C1    = 2.0f * GAMMA * LOG2E;   // exp2-domain scale on S
constexpr float GL    = GAMMA * LOG2E;

typedef __attribute__((ext_vector_type(8)))  short short8;
typedef __attribute__((ext_vector_type(16))) float f32x16;

#define MFMA(a, b, c) __builtin_amdgcn_mfma_f32_32x32x16_bf16((a), (b), (c), 0, 0, 0)

__device__ __forceinline__ float fexp2(float x) {
#if __has_builtin(__builtin_amdgcn_exp2f)
    return __builtin_amdgcn_exp2f(x);   // compiler-visible: MFMA->VALU hazards handled
#else
    return exp2f(x);
#endif
}

__device__ __forceinline__ unsigned short f2bf(float f) {
    union { float f; unsigned int u; } a; a.f = f;
    unsigned int u = a.u;
    return (unsigned short)((u + 0x7FFFu + ((u >> 16) & 1u)) >> 16);  // RNE
}

// ---------------------------------------------------------------------------
// prep_atoms (r13 verbatim): bfrag C1-scaled, can = -GL*||a||^2, kyy exact.
// B entry: lane l holds col (l&31), k = kt*16+(l>>5)*8+j, bfrag[c*256+kt*64+l].
// ---------------------------------------------------------------------------
__global__ __launch_bounds__(256) void prep_atoms(const float* __restrict__ atoms,
                                                  short8* __restrict__ bfrag,
                                                  float* __restrict__ can,
                                                  float* __restrict__ kyy) {
    const int c = blockIdx.x, t = threadIdx.x;
    __shared__ float a[KK][DD + 1];
    __shared__ float an[KK];
    __shared__ float wred[4];

    const float* ac = atoms + (size_t)c * KK * DD;
    for (int i = t; i < KK * DD; i += 256) a[i >> 6][i & 63] = ac[i];
    __syncthreads();

    if (t < KK) {
        float s = 0.f;
#pragma unroll
        for (int d = 0; d < DD; ++d) s = fmaf(a[t][d], a[t][d], s);
        an[t] = s;
        can[c * KK + t] = -GL * s;
    }
    __syncthreads();

    {   // fragment emit (scaled by C1)
        const int wv = t >> 6, l = t & 63;
        const int kp = l & 31, khh = l >> 5;
        short8 h;
#pragma unroll
        for (int j = 0; j < 8; ++j)
            h[j] = (short)f2bf(C1 * a[kp][wv * 16 + khh * 8 + j]);
        bfrag[(size_t)c * 256 + wv * 64 + l] = h;
    }

    {   // kyy (exact f32)
        const int i = t >> 3, j0 = (t & 7) * 4;
        float s0 = 0, s1 = 0, s2 = 0, s3 = 0;
        for (int d = 0; d < DD; ++d) {
            const float aid = a[i][d];
            s0 = fmaf(aid, a[j0 + 0][d], s0);
            s1 = fmaf(aid, a[j0 + 1][d], s1);
            s2 = fmaf(aid, a[j0 + 2][d], s2);
            s3 = fmaf(aid, a[j0 + 3][d], s3);
        }
        const float ani = an[i];
        float s = fexp2(-GL * (ani + an[j0 + 0] - 2.f * s0))
                + fexp2(-GL * (ani + an[j0 + 1] - 2.f * s1))
                + fexp2(-GL * (ani + an[j0 + 2] - 2.f * s2))
                + fexp2(-GL * (ani + an[j0 + 3] - 2.f * s3));
#pragma unroll
        for (int off = 32; off; off >>= 1) s += __shfl_xor(s, off);
        if ((t & 63) == 0) wred[t >> 6] = s;
    }
    __syncthreads();
    if (t == 0) kyy[c] = (wred[0] + wred[1] + wred[2] + wred[3]) * (1.0f / (KK * KK));
}

// ---------------------------------------------------------------------------
// mmd_fused: grid 1024 = (b, cq), block 256 = 4 waves, wave w = rowtile w.
// Prologue: A-build from x + norms + A->LDS exchange + cav table; barrier.
// kxx: 4 tiles, B = Axch[p] (ds_read, no further sync needed).
// atoms: 16 tiles, B global->reg with 2-deep prefetch, NO barriers.
// One barrier before the cross-wave tail reduce. Direct out write.
// ---------------------------------------------------------------------------
__global__ __launch_bounds__(256, 4) void mmd_fused(const float* __restrict__ x,
                                                    const short8* __restrict__ bfrag,
                                                    const float* __restrict__ can,
                                                    const float* __restrict__ kyy,
                                                    float* __restrict__ out) {
    const int bid = blockIdx.x, b = bid >> 2, cq = bid & 3;
    const int t = threadIdx.x, w = t >> 6, l = t & 63;
    const int l31 = l & 31, kh = l >> 5;

    __shared__ short8 Axch[4][256];       // 16 KB A-tile exchange (kxx B operands)
    __shared__ float  part16[4][20][16];  // 5 KB partials
    __shared__ float  nl[NODES];          // 512 B: -GL*||x_row||^2
    __shared__ float  cavl[16][32];       // 2 KB: -GL*||a||^2 for this quarter
    __shared__ float  sxy_s[16];
    __shared__ float  kxx_s;

    // ---- A-build: rowtile w from x (validated r6/r13 pattern) ----
    float v[32];
    {
        const float* xr = x + ((size_t)(b * NODES + w * 32 + l31)) * DD + kh * 8;
#pragma unroll
        for (int kt = 0; kt < 4; ++kt) {
            const float4 p0 = *reinterpret_cast<const float4*>(xr + kt * 16);
            const float4 p1 = *reinterpret_cast<const float4*>(xr + kt * 16 + 4);
            v[kt*8+0]=p0.x; v[kt*8+1]=p0.y; v[kt*8+2]=p0.z; v[kt*8+3]=p0.w;
            v[kt*8+4]=p1.x; v[kt*8+5]=p1.y; v[kt*8+6]=p1.z; v[kt*8+7]=p1.w;
        }
    }
    float xn = 0.f;
#pragma unroll
    for (int i = 0; i < 32; ++i) xn = fmaf(v[i], v[i], xn);
    xn += __shfl_xor(xn, 32);
    if (l < 32) nl[w * 32 + l] = -GL * xn;

    short8 A[4];
#pragma unroll
    for (int kt = 0; kt < 4; ++kt) {
        short8 h;
#pragma unroll
        for (int j = 0; j < 8; ++j) h[j] = (short)f2bf(v[kt * 8 + j]);
        A[kt] = h;
        Axch[w][kt * 64 + l] = h;         // kxx B-tile (A-layout == B-layout)
    }

    // cav table: -GL*||a||^2 for the 16 atoms of this quarter
    for (int i = t; i < 512; i += 256) cavl[i >> 5][i & 31] = can[cq * 512 + i];

    __syncthreads();                      // barrier 1: nl, Axch, cavl ready

    // cx: row-norm constants for this wave's acc rows
    f32x16 cx;
    {
        const float* nb = &nl[w * 32 + 4 * kh];
#pragma unroll
        for (int q = 0; q < 4; ++q) {
            const float4 vq = *reinterpret_cast<const float4*>(nb + 8 * q);
            cx[4*q+0] = vq.x; cx[4*q+1] = vq.y; cx[4*q+2] = vq.z; cx[4*q+3] = vq.w;
        }
    }

    // ---- kxx: 4 tiles from Axch ----
#pragma unroll
    for (int p = 0; p < 4; ++p) {
        short8 Bt[4];
#pragma unroll
        for (int kt = 0; kt < 4; ++kt) Bt[kt] = Axch[p][kt * 64 + l];
        f32x16 acc = {};
#pragma unroll
        for (int kt = 0; kt < 4; ++kt) acc = MFMA(A[kt], Bt[kt], acc);
        const float ec0 = fexp2(nl[p * 32 + l31]);
        float sa = 0.f, sb = 0.f;
#pragma unroll
        for (int r = 0; r < 16; r += 2) {
            sa += fexp2(fmaf(C1, acc[r],     cx[r]));
            sb += fexp2(fmaf(C1, acc[r + 1], cx[r + 1]));
        }
        float ssum = (sa + sb) * ec0;
        ssum += __shfl_xor(ssum, 32);
        ssum += __shfl_xor(ssum, 16);
        if (l < 16) part16[w][p][l] = ssum;
    }

    // ---- atoms: 16 tiles, B global->reg, 2-deep prefetch, no barriers ----
    const short8* bq = bfrag + (size_t)(cq * 16) * 256;
    short8 Breg[2][4];
#pragma unroll
    for (int kt = 0; kt < 4; ++kt) {
        Breg[0][kt] = bq[kt * 64 + l];
        Breg[1][kt] = bq[256 + kt * 64 + l];
    }
#pragma unroll
    for (int j = 0; j < 16; ++j) {
        const float ca = cavl[j][l31];
        f32x16 acc;
#pragma unroll
        for (int r = 0; r < 16; ++r) acc[r] = cx[r] + ca;
#pragma unroll
        for (int kt = 0; kt < 4; ++kt) acc = MFMA(A[kt], Breg[j & 1][kt], acc);
        if (j < 14) {   // refill the slot just consumed with tile j+2
#pragma unroll
            for (int kt = 0; kt < 4; ++kt)
                Breg[j & 1][kt] = bq[(size_t)(j + 2) * 256 + kt * 64 + l];
        }
        float sa = 0.f, sb = 0.f;
#pragma unroll
        for (int r = 0; r < 16; r += 2) {
            sa += fexp2(acc[r]);
            sb += fexp2(acc[r + 1]);
        }
        float ssum = sa + sb;
        ssum += __shfl_xor(ssum, 32);
        ssum += __shfl_xor(ssum, 16);
        if (l < 16) part16[w][4 + j][l] = ssum;
    }

    __syncthreads();                      // barrier 2: part16 complete

    // ---- tail: reduce + direct out ----
    {
        const int o = t >> 4, g = t & 15;   // o = atom 0..15 (slot o+4)
        float s1 = part16[0][4 + o][g] + part16[1][4 + o][g]
                 + part16[2][4 + o][g] + part16[3][4 + o][g];
        s1 += __shfl_xor(s1, 8);
        s1 += __shfl_xor(s1, 4);
        s1 += __shfl_xor(s1, 2);
        s1 += __shfl_xor(s1, 1);
        if (g == 0) sxy_s[o] = s1;
    }
    if (t < 16) {
        float kx = 0.f;
#pragma unroll
        for (int ww = 0; ww < 4; ++ww)
#pragma unroll
            for (int q = 0; q < 4; ++q) kx += part16[ww][q][t];
        kx += __shfl_xor(kx, 8);
        kx += __shfl_xor(kx, 4);
        kx += __shfl_xor(kx, 2);
        kx += __shfl_xor(kx, 1);
        if (t == 0) kxx_s = kx;
    }
    __syncthreads();
    if (t < 16) {
        out[(size_t)b * CC + cq * 16 + t] =
            kxx_s * (1.0f / 16384.0f) + kyy[cq * 16 + t] - sxy_s[t] * (1.0f / 2048.0f);
    }
}

extern "C" void kernel_launch(void* const* d_in, const int* in_sizes, int n_in,
                              void* d_out, int out_size, void* d_ws, size_t ws_size,
                              hipStream_t stream) {
    const float* x     = (const float*)d_in[0];   // [32768, 64]
    const float* atoms = (const float*)d_in[1];   // [64, 32, 64]
    float* out = (float*)d_out;                   // [256, 64]

    char* ws = (char*)d_ws;
    short8* bfrag = (short8*)(ws);                        // 256 KiB
    float*  can   = (float*) (ws + 262144);               // 8 KiB
    float*  kyy   = (float*) (ws + 270336);               // 256 B

    prep_atoms<<<dim3(CC),   dim3(256), 0, stream>>>(atoms, bfrag, can, kyy);
    mmd_fused <<<dim3(1024), dim3(256), 0, stream>>>(x, bfrag, can, kyy, out);
}